// Round 1
// baseline (151.162 us; speedup 1.0000x reference)
//
#include <hip/hip_runtime.h>

#define BATCH 64
#define H 1024
#define W 1024
#define RPB 16                 // rows per block strip
#define STRIPS (H / RPB)       // 64
#define NT 256                 // threads per block (W / 4)
#define NPART 10               // sum, max, num0..3, cnt0..3

// ---------------- Pass 1: per-strip partial reductions ----------------
__global__ __launch_bounds__(NT) void pass1_kernel(const float* __restrict__ x,
                                                   float* __restrict__ part) {
    const int strip = blockIdx.x;
    const int b = blockIdx.y;
    const int tid = threadIdx.x;
    const int c0 = tid * 4;
    const float* img = x + (size_t)b * H * W;
    const int r0 = strip * RPB;

    __shared__ float shLast[NT];
    __shared__ float shRed[4][NPART];

    float4 prev = make_float4(0.f, 0.f, 0.f, 0.f);
    if (r0 > 0) {
        prev = *(const float4*)(img + (size_t)(r0 - 1) * W + c0);
    }

    float s = 0.f, mx = 0.f;
    float num0 = 0.f, num1 = 0.f, num2 = 0.f, num3 = 0.f;
    float cnt0 = 0.f, cnt1 = 0.f, cnt2 = 0.f, cnt3 = 0.f;

    for (int r = r0; r < r0 + RPB; ++r) {
        float4 cur = *(const float4*)(img + (size_t)r * W + c0);
        __syncthreads();                 // protect shLast from previous iter
        shLast[tid] = cur.w;
        __syncthreads();
        float left = (tid == 0) ? 0.f : shLast[tid - 1];

        float px[4] = {cur.x, cur.y, cur.z, cur.w};
        float pl[4] = {left, cur.x, cur.y, cur.z};
        float pv[4] = {prev.x, prev.y, prev.z, prev.w};
        const bool first_row = (r == 0);

        #pragma unroll
        for (int j = 0; j < 4; ++j) {
            float gx = (tid == 0 && j == 0) ? 0.f : (px[j] - pl[j]);
            float gy = first_row ? 0.f : (px[j] - pv[j]);
            float m = sqrtf(gx * gx + gy * gy + 1e-8f);
            s += m;
            mx = fmaxf(mx, m);
            // quadrant bins of atan2(gy, gx + 1e-8):
            // bin0 [-pi,-pi/2) bin1 [-pi/2,0) bin2 [0,pi/2) bin3 [pi/2,pi)
            // angle == pi (gy==0, gxp<0) falls in NO bin.
            float gxp = gx + 1e-8f;
            bool bn0 = (gy < 0.f) && (gxp < 0.f);
            bool bn1 = (gy < 0.f) && (gxp >= 0.f);
            bool bn3 = (gy > 0.f) && (gxp <= 0.f);
            bool bn2 = ((gy > 0.f) && (gxp > 0.f)) || ((gy == 0.f) && (gxp >= 0.f));
            num0 += bn0 ? m : 0.f;  cnt0 += bn0 ? 1.f : 0.f;
            num1 += bn1 ? m : 0.f;  cnt1 += bn1 ? 1.f : 0.f;
            num2 += bn2 ? m : 0.f;  cnt2 += bn2 ? 1.f : 0.f;
            num3 += bn3 ? m : 0.f;  cnt3 += bn3 ? 1.f : 0.f;
        }
        prev = cur;
    }

    // 64-lane wave reduction (k==1 is max, others sum)
    float v[NPART] = {s, mx, num0, num1, num2, num3, cnt0, cnt1, cnt2, cnt3};
    #pragma unroll
    for (int k = 0; k < NPART; ++k) {
        #pragma unroll
        for (int o = 32; o > 0; o >>= 1) {
            float other = __shfl_down(v[k], o, 64);
            v[k] = (k == 1) ? fmaxf(v[k], other) : (v[k] + other);
        }
    }
    const int wave = tid >> 6;
    const int lane = tid & 63;
    if (lane == 0) {
        #pragma unroll
        for (int k = 0; k < NPART; ++k) shRed[wave][k] = v[k];
    }
    __syncthreads();
    if (tid == 0) {
        float* dst = part + ((size_t)b * STRIPS + strip) * NPART;
        #pragma unroll
        for (int k = 0; k < NPART; ++k) {
            float a = shRed[0][k], bb = shRed[1][k], c = shRed[2][k], d = shRed[3][k];
            dst[k] = (k == 1) ? fmaxf(fmaxf(a, bb), fmaxf(c, d)) : (a + bb + c + d);
        }
    }
}

// ---------------- Reduce partials -> mean + 6 features ----------------
__global__ __launch_bounds__(64) void reduce_kernel(const float* __restrict__ part,
                                                    float* __restrict__ out,
                                                    float* __restrict__ mean_ws,
                                                    unsigned int* __restrict__ count_ws) {
    const int b = blockIdx.x;
    const int t = threadIdx.x;  // one strip per lane
    const float* src = part + ((size_t)b * STRIPS + t) * NPART;
    float v[NPART];
    #pragma unroll
    for (int k = 0; k < NPART; ++k) v[k] = src[k];
    #pragma unroll
    for (int k = 0; k < NPART; ++k) {
        #pragma unroll
        for (int o = 32; o > 0; o >>= 1) {
            float other = __shfl_down(v[k], o, 64);
            v[k] = (k == 1) ? fmaxf(v[k], other) : (v[k] + other);
        }
    }
    if (t == 0) {
        const float invN = 1.0f / (float)(H * W);
        float mean = v[0] * invN;
        out[b * 7 + 1] = mean;                      // edge_strength (== mean_mag)
        out[b * 7 + 2] = v[1];                      // edge_max
        out[b * 7 + 3] = v[2] / (v[6] + 1e-8f);     // angle feats
        out[b * 7 + 4] = v[3] / (v[7] + 1e-8f);
        out[b * 7 + 5] = v[4] / (v[8] + 1e-8f);
        out[b * 7 + 6] = v[5] / (v[9] + 1e-8f);
        mean_ws[b] = mean;
        count_ws[b] = 0u;                           // zero for pass 2 atomics
    }
}

// ---------------- Pass 2: count grad_mag > mean ----------------
__global__ __launch_bounds__(NT) void pass2_kernel(const float* __restrict__ x,
                                                   const float* __restrict__ mean_ws,
                                                   unsigned int* __restrict__ count_ws) {
    const int strip = blockIdx.x;
    const int b = blockIdx.y;
    const int tid = threadIdx.x;
    const int c0 = tid * 4;
    const float* img = x + (size_t)b * H * W;
    const int r0 = strip * RPB;
    const float mean = mean_ws[b];

    __shared__ float shLast[NT];
    __shared__ unsigned int shCnt[4];

    float4 prev = make_float4(0.f, 0.f, 0.f, 0.f);
    if (r0 > 0) {
        prev = *(const float4*)(img + (size_t)(r0 - 1) * W + c0);
    }

    unsigned int cnt = 0;
    for (int r = r0; r < r0 + RPB; ++r) {
        float4 cur = *(const float4*)(img + (size_t)r * W + c0);
        __syncthreads();
        shLast[tid] = cur.w;
        __syncthreads();
        float left = (tid == 0) ? 0.f : shLast[tid - 1];

        float px[4] = {cur.x, cur.y, cur.z, cur.w};
        float pl[4] = {left, cur.x, cur.y, cur.z};
        float pv[4] = {prev.x, prev.y, prev.z, prev.w};
        const bool first_row = (r == 0);

        #pragma unroll
        for (int j = 0; j < 4; ++j) {
            float gx = (tid == 0 && j == 0) ? 0.f : (px[j] - pl[j]);
            float gy = first_row ? 0.f : (px[j] - pv[j]);
            float m = sqrtf(gx * gx + gy * gy + 1e-8f);
            cnt += (m > mean) ? 1u : 0u;
        }
        prev = cur;
    }

    #pragma unroll
    for (int o = 32; o > 0; o >>= 1) cnt += __shfl_down(cnt, o, 64);
    const int wave = tid >> 6;
    const int lane = tid & 63;
    if (lane == 0) shCnt[wave] = cnt;
    __syncthreads();
    if (tid == 0) {
        atomicAdd(count_ws + b, shCnt[0] + shCnt[1] + shCnt[2] + shCnt[3]);
    }
}

// ---------------- Finalize edge_density ----------------
__global__ void finalize_kernel(const unsigned int* __restrict__ count_ws,
                                float* __restrict__ out) {
    int b = threadIdx.x;
    if (b < BATCH) {
        out[b * 7 + 0] = (float)count_ws[b] * (1.0f / (float)(H * W));
    }
}

extern "C" void kernel_launch(void* const* d_in, const int* in_sizes, int n_in,
                              void* d_out, int out_size, void* d_ws, size_t ws_size,
                              hipStream_t stream) {
    const float* x = (const float*)d_in[0];
    float* out = (float*)d_out;

    float* part = (float*)d_ws;                                   // 64*64*10 floats
    float* mean_ws = part + (size_t)BATCH * STRIPS * NPART;       // 64 floats
    unsigned int* count_ws = (unsigned int*)(mean_ws + BATCH);    // 64 uints

    dim3 grid(STRIPS, BATCH);
    pass1_kernel<<<grid, NT, 0, stream>>>(x, part);
    reduce_kernel<<<BATCH, 64, 0, stream>>>(part, out, mean_ws, count_ws);
    pass2_kernel<<<grid, NT, 0, stream>>>(x, mean_ws, count_ws);
    finalize_kernel<<<1, 64, 0, stream>>>(count_ws, out);
}

// Round 2
// 112.544 us; speedup vs baseline: 1.3431x; 1.3431x over previous
//
#include <hip/hip_runtime.h>

#define BATCH 64
#define H 1024
#define W 1024
#define RPB 32                 // rows per block strip
#define STRIPS (H / RPB)       // 32
#define NT 256                 // threads per block (W / 4)
#define NPART 10               // sum, max, num0..3, cnt0..3
#define NBINS 1024
#define BIN_SCALE 64.0f        // bin = m * 64 -> range [0, 16)

// ---------------- Pass 1: partials + per-image histogram ----------------
__global__ __launch_bounds__(NT) void pass1_kernel(const float* __restrict__ x,
                                                   float* __restrict__ part,
                                                   unsigned int* __restrict__ hist) {
    const int strip = blockIdx.x;
    const int b = blockIdx.y;
    const int tid = threadIdx.x;
    const int wave = tid >> 6;
    const int lane = tid & 63;
    const int seg0 = wave << 8;           // wave's 256-col segment base
    const int col = seg0 + (lane << 2);
    const float* img = x + (size_t)b * H * W;
    const int r0 = strip * RPB;

    __shared__ unsigned int shHist[NBINS];
    __shared__ float shRed[4][NPART];

    for (int i = tid; i < NBINS; i += NT) shHist[i] = 0u;
    __syncthreads();

    float4 prev;
    if (r0 > 0) prev = *(const float4*)(img + (size_t)(r0 - 1) * W + col);
    else        prev = make_float4(0.f, 0.f, 0.f, 0.f);
    float4 nxt = *(const float4*)(img + (size_t)r0 * W + col);

    float s = 0.f, mx = 0.f;
    float num0 = 0.f, num1 = 0.f, num2 = 0.f, num3 = 0.f;
    float cnt0 = 0.f, cnt1 = 0.f, cnt2 = 0.f, cnt3 = 0.f;

    for (int r = r0; r < r0 + RPB; ++r) {
        float4 cur = nxt;
        if (r + 1 < r0 + RPB)
            nxt = *(const float4*)(img + (size_t)(r + 1) * W + col);   // prefetch

        // left neighbor of cur.x: previous lane's cur.w via shuffle;
        // wave boundary via one scalar load (lane 0 only)
        float lb = 0.f;
        if (lane == 0 && seg0 > 0) lb = img[(size_t)r * W + seg0 - 1];
        float sw = __shfl_up(cur.w, 1, 64);
        float left = (lane == 0) ? lb : sw;

        const bool first_row = (r == 0);
        float px[4] = {cur.x, cur.y, cur.z, cur.w};
        float pl[4] = {left, cur.x, cur.y, cur.z};
        float pv[4] = {prev.x, prev.y, prev.z, prev.w};

        #pragma unroll
        for (int j = 0; j < 4; ++j) {
            float gx = (col == 0 && j == 0) ? 0.f : (px[j] - pl[j]);
            float gy = first_row ? 0.f : (px[j] - pv[j]);
            float m = sqrtf(__builtin_fmaf(gx, gx, __builtin_fmaf(gy, gy, 1e-8f)));
            s += m;
            mx = fmaxf(mx, m);

            unsigned int bin = (unsigned int)(m * BIN_SCALE);
            bin = bin > (NBINS - 1) ? (NBINS - 1) : bin;
            atomicAdd(&shHist[bin], 1u);

            // quadrant bins of atan2(gy, gx + 1e-8):
            // bin0 [-pi,-pi/2) bin1 [-pi/2,0) bin2 [0,pi/2) bin3 [pi/2,pi)
            // angle == pi (gy==0, gxp<0) falls in NO bin.
            float gxp = gx + 1e-8f;
            bool bn0 = (gy < 0.f) && (gxp < 0.f);
            bool bn1 = (gy < 0.f) && (gxp >= 0.f);
            bool bn3 = (gy > 0.f) && (gxp <= 0.f);
            bool bn2 = ((gy > 0.f) && (gxp > 0.f)) || ((gy == 0.f) && (gxp >= 0.f));
            num0 += bn0 ? m : 0.f;  cnt0 += bn0 ? 1.f : 0.f;
            num1 += bn1 ? m : 0.f;  cnt1 += bn1 ? 1.f : 0.f;
            num2 += bn2 ? m : 0.f;  cnt2 += bn2 ? 1.f : 0.f;
            num3 += bn3 ? m : 0.f;  cnt3 += bn3 ? 1.f : 0.f;
        }
        prev = cur;
    }

    // 64-lane wave reduction (k==1 is max, others sum)
    float v[NPART] = {s, mx, num0, num1, num2, num3, cnt0, cnt1, cnt2, cnt3};
    #pragma unroll
    for (int k = 0; k < NPART; ++k) {
        #pragma unroll
        for (int o = 32; o > 0; o >>= 1) {
            float other = __shfl_down(v[k], o, 64);
            v[k] = (k == 1) ? fmaxf(v[k], other) : (v[k] + other);
        }
    }
    if (lane == 0) {
        #pragma unroll
        for (int k = 0; k < NPART; ++k) shRed[wave][k] = v[k];
    }
    __syncthreads();
    if (tid == 0) {
        float* dst = part + ((size_t)b * STRIPS + strip) * NPART;
        #pragma unroll
        for (int k = 0; k < NPART; ++k) {
            float a = shRed[0][k], bb = shRed[1][k], c = shRed[2][k], d = shRed[3][k];
            dst[k] = (k == 1) ? fmaxf(fmaxf(a, bb), fmaxf(c, d)) : (a + bb + c + d);
        }
    }

    // flush histogram (skip empty bins to cut global atomics)
    unsigned int* gh = hist + (size_t)b * NBINS;
    for (int i = tid; i < NBINS; i += NT) {
        unsigned int hv = shHist[i];
        if (hv) atomicAdd(gh + i, hv);
    }
}

// ---------------- Finalize: partials -> features, hist -> density ----------------
__global__ __launch_bounds__(NT) void finalize_kernel(const float* __restrict__ part,
                                                      const unsigned int* __restrict__ hist,
                                                      float* __restrict__ out) {
    const int b = blockIdx.x;
    const int tid = threadIdx.x;
    __shared__ float shMean;
    __shared__ float shCnt[4];

    if (tid < 64) {
        float v[NPART];
        #pragma unroll
        for (int k = 0; k < NPART; ++k) v[k] = 0.f;
        if (tid < STRIPS) {
            const float* src = part + ((size_t)b * STRIPS + tid) * NPART;
            #pragma unroll
            for (int k = 0; k < NPART; ++k) v[k] = src[k];
        }
        #pragma unroll
        for (int k = 0; k < NPART; ++k) {
            #pragma unroll
            for (int o = 32; o > 0; o >>= 1) {
                float other = __shfl_down(v[k], o, 64);
                v[k] = (k == 1) ? fmaxf(v[k], other) : (v[k] + other);
            }
        }
        if (tid == 0) {
            const float invN = 1.0f / (float)(H * W);
            float mean = v[0] * invN;
            out[b * 7 + 1] = mean;                      // edge_strength (== mean_mag)
            out[b * 7 + 2] = v[1];                      // edge_max
            out[b * 7 + 3] = v[2] / (v[6] + 1e-8f);     // angle feats
            out[b * 7 + 4] = v[3] / (v[7] + 1e-8f);
            out[b * 7 + 5] = v[4] / (v[8] + 1e-8f);
            out[b * 7 + 6] = v[5] / (v[9] + 1e-8f);
            shMean = mean;
        }
    }
    __syncthreads();

    const float mean = shMean;
    float mb = mean * BIN_SCALE;
    int k = (int)mb;
    if (k > NBINS - 1) k = NBINS - 1;
    const float frac = mb - (float)k;

    float c = 0.f;
    const unsigned int* gh = hist + (size_t)b * NBINS;
    for (int i = tid; i < NBINS; i += NT) {
        float h = (float)gh[i];
        c += (i > k) ? h : ((i == k) ? h * (1.0f - frac) : 0.f);
    }
    #pragma unroll
    for (int o = 32; o > 0; o >>= 1) c += __shfl_down(c, o, 64);
    const int wv = tid >> 6, ln = tid & 63;
    if (ln == 0) shCnt[wv] = c;
    __syncthreads();
    if (tid == 0) {
        float total = shCnt[0] + shCnt[1] + shCnt[2] + shCnt[3];
        out[b * 7 + 0] = total * (1.0f / (float)(H * W));
    }
}

extern "C" void kernel_launch(void* const* d_in, const int* in_sizes, int n_in,
                              void* d_out, int out_size, void* d_ws, size_t ws_size,
                              hipStream_t stream) {
    const float* x = (const float*)d_in[0];
    float* out = (float*)d_out;

    unsigned int* hist = (unsigned int*)d_ws;                       // 64*1024 uints
    float* part = (float*)((char*)d_ws + (size_t)BATCH * NBINS * 4); // 64*32*10 floats

    hipMemsetAsync(hist, 0, (size_t)BATCH * NBINS * sizeof(unsigned int), stream);

    dim3 grid(STRIPS, BATCH);
    pass1_kernel<<<grid, NT, 0, stream>>>(x, part, hist);
    finalize_kernel<<<BATCH, NT, 0, stream>>>(part, hist, out);
}

// Round 3
// 92.616 us; speedup vs baseline: 1.6321x; 1.2152x over previous
//
#include <hip/hip_runtime.h>

#define BATCH 64
#define H 1024
#define W 1024
#define RPB 32                 // rows per block strip
#define STRIPS (H / RPB)       // 32
#define NT 256                 // threads per block (W / 4)
#define NB 512                 // magnitude bins per region
#define NREG 5                 // quadrants 0..3 + no-bin region 4
#define NHIST (NREG * NB)      // 2560
#define BIN_SCALE 32.0f        // bin = m * 32 -> range [0, 16)

// Process one row of 4 pixels. FIRST = row 0 of the image (gy forced 0).
template<bool FIRST>
__device__ __forceinline__ void do_row(float4 cur, float4 prevv, float left, int col,
                                       float& s, float& mx, unsigned int* shHist) {
    float px[4] = {cur.x, cur.y, cur.z, cur.w};
    float pl[4] = {left, cur.x, cur.y, cur.z};
    float pv[4] = {prevv.x, prevv.y, prevv.z, prevv.w};
    #pragma unroll
    for (int j = 0; j < 4; ++j) {
        float gx = px[j] - pl[j];
        if (j == 0) gx = (col == 0) ? 0.f : gx;     // zero-pad first column
        float gy = FIRST ? 0.f : (px[j] - pv[j]);
        float m = sqrtf(__builtin_fmaf(gx, gx, __builtin_fmaf(gy, gy, 1e-8f)));
        s += m;
        mx = fmaxf(mx, m);
        unsigned int bin = (unsigned int)(m * BIN_SCALE);
        bin = bin > (NB - 1) ? (NB - 1) : bin;
        // quadrant from sign bits of gy and gxp = gx + 1e-8:
        //   (sy,sxp)=(1,1)->q0 [-pi,-pi/2) ; (1,0)->q1 [-pi/2,0)
        //   (0,0)->q2 [0,pi/2)            ; (0,1)->q3 [pi/2,pi)
        // row 0 (gy==0): atan2(0,gxp) = 0 (q2) if gxp>=0, = pi (NO bin, q4) if gxp<0
        unsigned int sxp = __float_as_uint(gx + 1e-8f) >> 31;
        unsigned int q;
        if (FIRST) {
            q = sxp ? 4u : 2u;
        } else {
            unsigned int sy = __float_as_uint(gy) >> 31;
            q = ((sy ^ 1u) << 1) | (sxp ^ sy);
        }
        atomicAdd(&shHist[q * NB + bin], 1u);
    }
}

// ---------------- Pass 1: per-strip {sum,max} + 5-region histogram ----------------
__global__ __launch_bounds__(NT) void pass1_kernel(const float* __restrict__ x,
                                                   float* __restrict__ part,
                                                   unsigned int* __restrict__ hist) {
    const int strip = blockIdx.x;
    const int b = blockIdx.y;
    const int tid = threadIdx.x;
    const int wave = tid >> 6;
    const int lane = tid & 63;
    const int seg0 = wave << 8;           // wave's 256-col segment base
    const int col = seg0 + (lane << 2);
    const float* img = x + (size_t)b * H * W;
    const int r0 = strip * RPB;

    __shared__ unsigned int shHist[NHIST];
    __shared__ float shRed[4][2];

    for (int i = tid; i < NHIST; i += NT) shHist[i] = 0u;
    __syncthreads();

    float s = 0.f, mx = 0.f;
    float4 prev, nxt;
    int r_begin;
    if (r0 == 0) {
        // peel row 0 (gy == 0 path with the no-bin case)
        float4 cur0 = *(const float4*)(img + col);
        float lb = 0.f;
        if (lane == 0 && seg0 > 0) lb = img[seg0 - 1];
        float sw = __shfl_up(cur0.w, 1, 64);
        float left = (lane == 0) ? lb : sw;
        do_row<true>(cur0, cur0, left, col, s, mx, shHist);
        prev = cur0;
        r_begin = 1;
        nxt = *(const float4*)(img + (size_t)W + col);
    } else {
        prev = *(const float4*)(img + (size_t)(r0 - 1) * W + col);
        r_begin = r0;
        nxt = *(const float4*)(img + (size_t)r0 * W + col);
    }

    for (int r = r_begin; r < r0 + RPB; ++r) {
        float4 cur = nxt;
        if (r + 1 < r0 + RPB)
            nxt = *(const float4*)(img + (size_t)(r + 1) * W + col);   // prefetch
        float lb = 0.f;
        if (lane == 0 && seg0 > 0) lb = img[(size_t)r * W + seg0 - 1];
        float sw = __shfl_up(cur.w, 1, 64);
        float left = (lane == 0) ? lb : sw;
        do_row<false>(cur, prev, left, col, s, mx, shHist);
        prev = cur;
    }

    // wave reduce: s (sum), mx (max)
    #pragma unroll
    for (int o = 32; o > 0; o >>= 1) {
        s += __shfl_down(s, o, 64);
        mx = fmaxf(mx, __shfl_down(mx, o, 64));
    }
    if (lane == 0) { shRed[wave][0] = s; shRed[wave][1] = mx; }
    __syncthreads();    // also guarantees all shHist atomics are complete
    if (tid == 0) {
        float* dst = part + (size_t)(b * STRIPS + strip) * 2;
        dst[0] = shRed[0][0] + shRed[1][0] + shRed[2][0] + shRed[3][0];
        dst[1] = fmaxf(fmaxf(shRed[0][1], shRed[1][1]), fmaxf(shRed[2][1], shRed[3][1]));
    }

    // flush per-strip histogram (plain coalesced stores, no atomics)
    unsigned int* gh = hist + (size_t)(b * STRIPS + strip) * NHIST;
    for (int i = tid; i < NHIST; i += NT) gh[i] = shHist[i];
}

// ---------------- Finalize: one block per image ----------------
__global__ __launch_bounds__(NT) void finalize_kernel(const float* __restrict__ part,
                                                      const unsigned int* __restrict__ hist,
                                                      float* __restrict__ out) {
    const int b = blockIdx.x;
    const int tid = threadIdx.x;
    __shared__ unsigned int shH[NHIST];
    __shared__ float shMean;
    __shared__ float shRed[4][9];

    // sum the 32 per-strip histograms (exact integer adds)
    for (int f = tid; f < NHIST; f += NT) {
        unsigned int acc = 0;
        const unsigned int* src = hist + (size_t)b * STRIPS * NHIST + f;
        #pragma unroll 4
        for (int s2 = 0; s2 < STRIPS; ++s2) acc += src[(size_t)s2 * NHIST];
        shH[f] = acc;
    }

    // reduce per-strip {sum, max}
    if (tid < 64) {
        float vs = 0.f, vm = 0.f;
        if (tid < STRIPS) {
            const float* src = part + (size_t)(b * STRIPS + tid) * 2;
            vs = src[0]; vm = src[1];
        }
        #pragma unroll
        for (int o = 32; o > 0; o >>= 1) {
            vs += __shfl_down(vs, o, 64);
            vm = fmaxf(vm, __shfl_down(vm, o, 64));
        }
        if (tid == 0) {
            float mean = vs * (1.0f / (float)(H * W));
            out[b * 7 + 1] = mean;      // edge_strength (== mean_mag)
            out[b * 7 + 2] = vm;        // edge_max
            shMean = mean;
        }
    }
    __syncthreads();

    const float mean = shMean;
    float mb = mean * BIN_SCALE;
    int k = (int)mb;
    if (k > NB - 1) k = NB - 1;
    const float frac = mb - (float)k;

    // per-quadrant {count, sum-of-centers} + density count above mean
    float sq0 = 0.f, sq1 = 0.f, sq2 = 0.f, sq3 = 0.f;
    float cq0 = 0.f, cq1 = 0.f, cq2 = 0.f, cq3 = 0.f;
    float dens = 0.f;
    #pragma unroll
    for (int q = 0; q < NREG; ++q) {
        #pragma unroll
        for (int ii = 0; ii < NB; ii += NT) {
            int i = ii + tid;
            float hf = (float)shH[q * NB + i];
            float ctr = ((float)i + 0.5f) * (1.0f / BIN_SCALE);
            if (q == 0) { cq0 += hf; sq0 += hf * ctr; }
            if (q == 1) { cq1 += hf; sq1 += hf * ctr; }
            if (q == 2) { cq2 += hf; sq2 += hf * ctr; }
            if (q == 3) { cq3 += hf; sq3 += hf * ctr; }
            dens += (i > k) ? hf : ((i == k) ? hf * (1.0f - frac) : 0.f);
        }
    }

    float v[9] = {sq0, sq1, sq2, sq3, cq0, cq1, cq2, cq3, dens};
    #pragma unroll
    for (int kk = 0; kk < 9; ++kk) {
        #pragma unroll
        for (int o = 32; o > 0; o >>= 1)
            v[kk] += __shfl_down(v[kk], o, 64);
    }
    const int wv = tid >> 6, ln = tid & 63;
    if (ln == 0) {
        #pragma unroll
        for (int kk = 0; kk < 9; ++kk) shRed[wv][kk] = v[kk];
    }
    __syncthreads();
    if (tid == 0) {
        float t[9];
        #pragma unroll
        for (int kk = 0; kk < 9; ++kk)
            t[kk] = shRed[0][kk] + shRed[1][kk] + shRed[2][kk] + shRed[3][kk];
        out[b * 7 + 0] = t[8] * (1.0f / (float)(H * W));   // edge_density
        out[b * 7 + 3] = t[0] / (t[4] + 1e-8f);            // angle features
        out[b * 7 + 4] = t[1] / (t[5] + 1e-8f);
        out[b * 7 + 5] = t[2] / (t[6] + 1e-8f);
        out[b * 7 + 6] = t[3] / (t[7] + 1e-8f);
    }
}

extern "C" void kernel_launch(void* const* d_in, const int* in_sizes, int n_in,
                              void* d_out, int out_size, void* d_ws, size_t ws_size,
                              hipStream_t stream) {
    const float* x = (const float*)d_in[0];
    float* out = (float*)d_out;

    unsigned int* hist = (unsigned int*)d_ws;                 // 64*32*2560 u32 = 21 MB
    float* part = (float*)(hist + (size_t)BATCH * STRIPS * NHIST);  // 64*32*2 floats

    dim3 grid(STRIPS, BATCH);
    pass1_kernel<<<grid, NT, 0, stream>>>(x, part, hist);
    finalize_kernel<<<BATCH, NT, 0, stream>>>(part, hist, out);
}